// Round 1
// baseline (402.314 us; speedup 1.0000x reference)
//
#include <hip/hip_runtime.h>

#define DIN 256
#define DHID 128
#define DOUTD 64

// ---------------------------------------------------------------- GEMM
// C[M,N] = A[M,K] @ W[K,N].  BM=64, BK=32, BN=N (full width), 256 threads.
template<int N, int TN>
__global__ __launch_bounds__(256) void gemm_kernel(
    const float* __restrict__ A, const float* __restrict__ W,
    float* __restrict__ C, int M, int K)
{
    constexpr int BM = 64, BK = 32;
    constexpr int TX = N / TN;        // threads along N
    constexpr int TY = 256 / TX;      // threads along M
    constexpr int TM = BM / TY;       // rows per thread
    static_assert(TM == 4, "TM must be 4");

    __shared__ float As[BK][BM];      // transposed A tile
    __shared__ float Bs[BK][N];

    const int tid = threadIdx.x;
    const int tx = tid % TX, ty = tid / TX;
    const int row0 = blockIdx.x * BM;

    float acc[TM][TN] = {};

    for (int kb = 0; kb < K; kb += BK) {
        // A tile: BM x BK, float4 over k
        constexpr int AU = BM * (BK / 4);             // float4 units
        #pragma unroll
        for (int u = tid; u < AU; u += 256) {
            int r  = u / (BK / 4);
            int k4 = u % (BK / 4);
            float4 v = make_float4(0.f, 0.f, 0.f, 0.f);
            int gr = row0 + r;
            if (gr < M)
                v = *reinterpret_cast<const float4*>(&A[(size_t)gr * K + kb + k4 * 4]);
            As[k4 * 4 + 0][r] = v.x;
            As[k4 * 4 + 1][r] = v.y;
            As[k4 * 4 + 2][r] = v.z;
            As[k4 * 4 + 3][r] = v.w;
        }
        // B tile: BK x N, contiguous copy
        constexpr int BU = BK * (N / 4);
        #pragma unroll
        for (int u = tid; u < BU; u += 256) {
            int k  = u / (N / 4);
            int c4 = u % (N / 4);
            *reinterpret_cast<float4*>(&Bs[k][c4 * 4]) =
                *reinterpret_cast<const float4*>(&W[(size_t)(kb + k) * N + c4 * 4]);
        }
        __syncthreads();

        #pragma unroll
        for (int k = 0; k < BK; ++k) {
            float a[TM];
            float4 av = *reinterpret_cast<const float4*>(&As[k][ty * TM]);
            a[0] = av.x; a[1] = av.y; a[2] = av.z; a[3] = av.w;
            float b[TN];
            #pragma unroll
            for (int j = 0; j < TN; j += 4) {
                float4 bv = *reinterpret_cast<const float4*>(&Bs[k][tx * TN + j]);
                b[j] = bv.x; b[j + 1] = bv.y; b[j + 2] = bv.z; b[j + 3] = bv.w;
            }
            #pragma unroll
            for (int i = 0; i < TM; ++i)
                #pragma unroll
                for (int j = 0; j < TN; ++j)
                    acc[i][j] += a[i] * b[j];
        }
        __syncthreads();
    }

    #pragma unroll
    for (int i = 0; i < TM; ++i) {
        int gr = row0 + ty * TM + i;
        if (gr < M) {
            #pragma unroll
            for (int j = 0; j < TN; j += 4) {
                float4 v = make_float4(acc[i][j], acc[i][j + 1], acc[i][j + 2], acc[i][j + 3]);
                *reinterpret_cast<float4*>(&C[(size_t)gr * N + tx * TN + j]) = v;
            }
        }
    }
}

// ---------------------------------------------------------------- alpha dots
// asrc[i] = h[i] . a_s ; adst[i] = h[i] . a_d.  One wave per node.
template<int D>
__global__ __launch_bounds__(256) void alpha_kernel(
    const float* __restrict__ H, const float* __restrict__ a_s,
    const float* __restrict__ a_d, float* __restrict__ asrc,
    float* __restrict__ adst, int n)
{
    int wave = (blockIdx.x * blockDim.x + threadIdx.x) >> 6;
    int lane = threadIdx.x & 63;
    if (wave >= n) return;
    const float* h = H + (size_t)wave * D;
    float vs = 0.f, vd = 0.f;
    #pragma unroll
    for (int j = lane; j < D; j += 64) {
        float hv = h[j];
        vs += hv * a_s[j];
        vd += hv * a_d[j];
    }
    #pragma unroll
    for (int off = 32; off; off >>= 1) {
        vs += __shfl_xor(vs, off);
        vd += __shfl_xor(vd, off);
    }
    if (lane == 0) { asrc[wave] = vs; adst[wave] = vd; }
}

// ---------------------------------------------------------------- CSR build
__global__ void hist_kernel(const int* __restrict__ ei, int E, int n, int* __restrict__ deg)
{
    int e = blockIdx.x * blockDim.x + threadIdx.x;
    int ET = E + n;
    if (e >= ET) return;
    int d = (e < E) ? ei[E + e] : (e - E);
    atomicAdd(&deg[d], 1);
}

__global__ void scan1_kernel(const int* __restrict__ deg, int n,
                             int* __restrict__ S, int* __restrict__ part)
{
    __shared__ int sm[256];
    int i = blockIdx.x * 256 + threadIdx.x;
    int v = (i < n) ? deg[i] : 0;
    sm[threadIdx.x] = v;
    __syncthreads();
    for (int off = 1; off < 256; off <<= 1) {
        int t = (threadIdx.x >= off) ? sm[threadIdx.x - off] : 0;
        __syncthreads();
        sm[threadIdx.x] += t;
        __syncthreads();
    }
    if (i < n) S[i] = sm[threadIdx.x];
    if (threadIdx.x == 255) part[blockIdx.x] = sm[255];
}

__global__ void scan2_kernel(int* __restrict__ part, int nb)
{
    __shared__ int sm[256];
    int v = (threadIdx.x < nb) ? part[threadIdx.x] : 0;
    sm[threadIdx.x] = v;
    __syncthreads();
    for (int off = 1; off < 256; off <<= 1) {
        int t = (threadIdx.x >= off) ? sm[threadIdx.x - off] : 0;
        __syncthreads();
        sm[threadIdx.x] += t;
        __syncthreads();
    }
    if (threadIdx.x < nb)
        part[threadIdx.x] = (threadIdx.x == 0) ? 0 : sm[threadIdx.x - 1];
}

__global__ void scan3_kernel(const int* __restrict__ S, const int* __restrict__ part,
                             int n, int* __restrict__ offs)
{
    int i = blockIdx.x * 256 + threadIdx.x;
    if (i < n) offs[i + 1] = S[i] + part[i / 256];
    if (i == 0) offs[0] = 0;
}

__global__ void cursor_kernel(const int* __restrict__ offs, int n, int* __restrict__ cur)
{
    int i = blockIdx.x * 256 + threadIdx.x;
    if (i < n) cur[i] = offs[i];
}

__global__ void scatter_kernel(const int* __restrict__ ei, int E, int n,
                               int* __restrict__ cur, int* __restrict__ csr_src)
{
    int e = blockIdx.x * blockDim.x + threadIdx.x;
    int ET = E + n;
    if (e >= ET) return;
    int s, d;
    if (e < E) { s = ei[e]; d = ei[E + e]; }
    else       { s = e - E; d = s; }
    int pos = atomicAdd(&cur[d], 1);
    csr_src[pos] = s;
}

// ---------------------------------------------------------------- aggregation
// One block (D threads) per dst node: softmax over incoming edges + weighted sum.
template<int D, bool RELU>
__global__ __launch_bounds__(D) void agg_kernel(
    const float* __restrict__ H, const float* __restrict__ asrc,
    const float* __restrict__ adst, const int* __restrict__ offs,
    const int* __restrict__ csr_src, const float* __restrict__ bias,
    float* __restrict__ out)
{
    const int node = blockIdx.x;
    const int tid = threadIdx.x;
    const int beg = offs[node];
    const int deg = offs[node + 1] - beg;
    const float ad = adst[node];

    __shared__ float wred[2];
    __shared__ float wbuf[D];
    __shared__ int   sbuf[D];

    // pass 1: max logit
    float m = -1e30f;
    for (int k = tid; k < deg; k += D) {
        int s = csr_src[beg + k];
        float l = asrc[s] + ad;
        l = (l > 0.f) ? l : 0.2f * l;
        m = fmaxf(m, l);
    }
    #pragma unroll
    for (int off = 32; off; off >>= 1) m = fmaxf(m, __shfl_xor(m, off));
    if (D == 128) {
        if ((tid & 63) == 0) wred[tid >> 6] = m;
        __syncthreads();
        m = fmaxf(wred[0], wred[1]);
        __syncthreads();
    }

    // pass 2: sum of exp
    float ssum = 0.f;
    for (int k = tid; k < deg; k += D) {
        int s = csr_src[beg + k];
        float l = asrc[s] + ad;
        l = (l > 0.f) ? l : 0.2f * l;
        ssum += __expf(l - m);
    }
    #pragma unroll
    for (int off = 32; off; off >>= 1) ssum += __shfl_xor(ssum, off);
    if (D == 128) {
        if ((tid & 63) == 0) wred[tid >> 6] = ssum;
        __syncthreads();
        ssum = wred[0] + wred[1];
        __syncthreads();
    }
    const float inv = 1.f / ssum;

    // pass 3: weighted accumulate, tiles of D edges
    float acc = 0.f;
    for (int base = 0; base < deg; base += D) {
        int k = base + tid;
        if (k < deg) {
            int s = csr_src[beg + k];
            float l = asrc[s] + ad;
            l = (l > 0.f) ? l : 0.2f * l;
            wbuf[tid] = __expf(l - m) * inv;
            sbuf[tid] = s;
        }
        __syncthreads();
        int lim = min(D, deg - base);
        for (int kk = 0; kk < lim; ++kk)
            acc += wbuf[kk] * H[(size_t)sbuf[kk] * D + tid];
        __syncthreads();
    }

    float r = acc + bias[tid];
    if (RELU) r = fmaxf(r, 0.f);
    out[(size_t)node * D + tid] = r;
}

// ---------------------------------------------------------------- launch
extern "C" void kernel_launch(void* const* d_in, const int* in_sizes, int n_in,
                              void* d_out, int out_size, void* d_ws, size_t ws_size,
                              hipStream_t stream)
{
    const float* x   = (const float*)d_in[0];
    const int*   ei  = (const int*)  d_in[1];
    const float* W1  = (const float*)d_in[2];
    const float* as1 = (const float*)d_in[3];
    const float* ad1 = (const float*)d_in[4];
    const float* b1  = (const float*)d_in[5];
    const float* W2  = (const float*)d_in[6];
    const float* as2 = (const float*)d_in[7];
    const float* ad2 = (const float*)d_in[8];
    const float* b2  = (const float*)d_in[9];
    float* out = (float*)d_out;

    const int n  = in_sizes[0] / DIN;   // 50000
    const int E  = in_sizes[1] / 2;     // 800000
    const int ET = E + n;               // 850000

    char* ws = (char*)d_ws;
    size_t off = 0;
    auto alloc = [&](size_t bytes) -> void* {
        off = (off + 255) & ~(size_t)255;
        void* p = ws + off;
        off += bytes;
        return p;
    };
    float* H1   = (float*)alloc((size_t)n * DHID * 4);  // layer-1 h; reused as layer-2 h
    float* O1   = (float*)alloc((size_t)n * DHID * 4);  // layer-1 output (relu'd)
    float* asrc = (float*)alloc((size_t)n * 4);
    float* adst = (float*)alloc((size_t)n * 4);
    int* deg    = (int*)alloc((size_t)n * 4);
    int* S      = (int*)alloc((size_t)n * 4);
    int* part   = (int*)alloc(256 * 4);
    int* offs   = (int*)alloc((size_t)(n + 1) * 4);
    int* cur    = (int*)alloc((size_t)n * 4);
    int* csr    = (int*)alloc((size_t)ET * 4);

    const int nb = (n + 255) / 256;     // scan blocks (196)

    // ---- CSR build (graph identical for both layers)
    hipMemsetAsync(deg, 0, (size_t)n * 4, stream);
    hist_kernel<<<(ET + 255) / 256, 256, 0, stream>>>(ei, E, n, deg);
    scan1_kernel<<<nb, 256, 0, stream>>>(deg, n, S, part);
    scan2_kernel<<<1, 256, 0, stream>>>(part, nb);
    scan3_kernel<<<nb, 256, 0, stream>>>(S, part, n, offs);
    cursor_kernel<<<nb, 256, 0, stream>>>(offs, n, cur);
    scatter_kernel<<<(ET + 255) / 256, 256, 0, stream>>>(ei, E, n, cur, csr);

    // ---- layer 1
    gemm_kernel<DHID, 8><<<(n + 63) / 64, 256, 0, stream>>>(x, W1, H1, n, DIN);
    alpha_kernel<DHID><<<(n + 3) / 4, 256, 0, stream>>>(H1, as1, ad1, asrc, adst, n);
    agg_kernel<DHID, true><<<n, DHID, 0, stream>>>(H1, asrc, adst, offs, csr, b1, O1);

    // ---- layer 2
    gemm_kernel<DOUTD, 4><<<(n + 63) / 64, 256, 0, stream>>>(O1, W2, H1, n, DHID);
    alpha_kernel<DOUTD><<<(n + 3) / 4, 256, 0, stream>>>(H1, as2, ad2, asrc, adst, n);
    agg_kernel<DOUTD, false><<<n, DOUTD, 0, stream>>>(H1, asrc, adst, offs, csr, b2, out);
}